// Round 6
// baseline (49975.079 us; speedup 1.0000x reference)
//
#include <hip/hip_runtime.h>
#include <hip/hip_bf16.h>

// DecoderRNN: 3-layer GRU, B=512, S=200, H=1024, V=100, teacher-forced scan.
// Persistent-kernel v6: BATCH-partitioned across XCDs -> zero cross-XCD h.
//  - Each XCD owns 64 batch rows for the entire scan; h-state (768KB) stays
//    resident in that XCD's 4MB L2. No grid barrier, no MALL-coherent loads.
//  - Blocks self-assign (g = s_getreg(HW_REG_XCC_ID), c = atomicAdd slot):
//    correctness does NOT depend on blockIdx->XCD mapping. 256 blocks @
//    1 block/CU (120KB LDS) -> exactly 32 blocks per XCD.
//  - Within an XCD: 32 blocks split N (32 cols x 3 gates each; r4's proven
//    64Mx32N tile, 2Mx2K wave split, 3-slab staging, vmcnt(20)).
//  - XCD-local barrier: 32 sc0 flags in the XCD's L2 (~300cy, not ~3us).
//  - A (h) staging: aux=1 (sc0: bypass stale L1, hit local L2). W: aux=0,
//    streamed from L3 (every XCD reads all weights each step; L3-hot).
//  - h stores: sc0 (write-through to L2, XCD-local). Logits: NT stores.

typedef __hip_bfloat16 bf16;
typedef __attribute__((ext_vector_type(8))) short short8;
typedef __attribute__((ext_vector_type(8))) unsigned short ushort8;
typedef __attribute__((ext_vector_type(16))) float f32x16;

#define B_ 512
#define S_ 200
#define H_ 1024
#define V_ 100
#define NBLK 256
#define BUFSZ 40960

__device__ __forceinline__ float bf2f(bf16 x) { return __bfloat162float(x); }
__device__ __forceinline__ float us2f(unsigned short u) {
  return __uint_as_float(((unsigned)u) << 16);
}

// ---------------------------------------------------------------------------
// XCD-local barrier among the 32 blocks of XCD g. Arrival flags flags[g*64+c]
// live in this XCD's L2 (sc0 store/load: L1-bypassed, L2-served -> coherent
// for same-XCD blocks with no MALL traffic). Wave 0 lanes 0..31 poll; other
// waves park at the closing __syncthreads. Monotonic gen; sticky ~20ms
// timeout -> garbage-fast instead of hang.
// ---------------------------------------------------------------------------
__device__ __forceinline__ void xbar(unsigned* flags, int g, int c,
                                     unsigned gen, bool& dead) {
  __syncthreads();  // vmcnt(0): this block's sc0 h-stores are in L2
  const int tid = threadIdx.x;
  unsigned* base = flags + g * 64;
  if (tid == 0)
    asm volatile("global_store_dword %0, %1, off sc0"
                 :: "v"(base + c), "v"(gen) : "memory");
  if (tid < 64 && !dead) {
    unsigned long long t0 = __builtin_amdgcn_s_memrealtime();
    for (;;) {
      unsigned v = gen;
      if (tid < 32) {
        const unsigned* pp = base + tid;
        asm volatile("global_load_dword %0, %1, off sc0\n\t"
                     "s_waitcnt vmcnt(0)"
                     : "=v"(v) : "v"(pp) : "memory");
      }
      if (__all(v >= gen)) break;
      __builtin_amdgcn_s_sleep(2);
      if (__builtin_amdgcn_s_memrealtime() - t0 > 2000000ULL) {  // ~20 ms
        dead = true;
        break;
      }
    }
  }
  __syncthreads();
}

// ---------------------------------------------------------------------------
// Gates tile: 64M x 32N x 3 gates of h_l(t) for rows [rowbase, rowbase+64).
// 4 waves: wm = w&1 (M-half), ks = w>>1 (K-half). 3-slab staging (40KB each),
// 2-deep prefetch, counted vmcnt. GRU epilogue on ks==0 waves with
// register-resident hprev; h stores sc0 (XCD-local L2).
// ---------------------------------------------------------------------------
template <int KTOT, bool L0T>
__device__ __forceinline__ void gates_tile(
    int rowbase, int nb,
    const bf16* __restrict__ A0,      // k in [0,1024)
    const bf16* __restrict__ A1,      // k in [1024,2048) (unused if KTOT=1024)
    const bf16* __restrict__ Wp,      // [3][1024][KTOT]
    const float* __restrict__ bias4,  // [4][1024]
    const float* __restrict__ table,  // [100][3072] (L0 only)
    const float* __restrict__ gprec,  // [512][3072] (L0 only)
    const int* __restrict__ inputs,   // [512][200]  (L0 only)
    int t,
    bf16* __restrict__ hout,          // h_l(t) [512][1024]
    unsigned (&hreg)[8],              // hprev bits, 2 bf16/word (ks0 only)
    char* smem)
{
  constexpr int KH = KTOT / 2;
  constexpr int NITER = KH / 64;
  const int tid = threadIdx.x;
  const int lane = tid & 63;
  const int w = tid >> 6;
  const int wm = w & 1, ks = w >> 1;

  __syncthreads();  // previous phase's smem fully consumed

  // ---- staging source pointers; +128B per k-slab ----
  // c<4: A granule [ksA][row 0..63][kcs 0..7], kc = kcs ^ (row&7), aux=1
  //      (sc0: bypass L1, hit XCD-local L2 where h was written).
  // c>=4: W granule [g][ksB][nl 0..31][kcs 0..7], aux=0 (normal cached).
  const char* gp[10];
#pragma unroll
  for (int c = 0; c < 10; ++c) {
    const int G = c * 256 + tid;
    if (c < 4) {
      int ksA = G >> 9, row = (G >> 3) & 63, kcs = G & 7;
      int kc = kcs ^ (row & 7);
      int k = ksA * KH + kc * 8;
      const bf16* src = (KTOT == 2048 && k >= 1024) ? A1 : A0;
      gp[c] = (const char*)(src + ((rowbase + row) * H_ + (k & 1023)));
    } else {
      int Gb = G - 1024;
      int g = Gb >> 9, ksB = (Gb >> 8) & 1, nl = (Gb >> 3) & 31, kcs = Gb & 7;
      int kc = kcs ^ (nl & 7);
      int k0 = ksB * KH + kc * 8;
      gp[c] = (const char*)(Wp + ((g * 1024 + nb * 32 + nl) * KTOT + k0));
    }
  }

#define STAGE(slot)                                                          \
  do {                                                                       \
    char* lbase = smem + (slot) * BUFSZ + (w * 64) * 16;                     \
    _Pragma("unroll")                                                        \
    for (int c = 0; c < 10; ++c) {                                           \
      if (c < 4)                                                             \
        __builtin_amdgcn_global_load_lds(                                    \
            (const __attribute__((address_space(1))) void*)gp[c],            \
            (__attribute__((address_space(3))) void*)(lbase + c * 4096),     \
            16, 0, 1 /* sc0 */);                                             \
      else                                                                   \
        __builtin_amdgcn_global_load_lds(                                    \
            (const __attribute__((address_space(1))) void*)gp[c],            \
            (__attribute__((address_space(3))) void*)(lbase + c * 4096),     \
            16, 0, 0);                                                       \
      gp[c] += 128;                                                          \
    }                                                                        \
  } while (0)

  f32x16 accR, accZ, accN;
#pragma unroll
  for (int j = 0; j < 16; ++j) { accR[j] = 0.f; accZ[j] = 0.f; accN[j] = 0.f; }

  STAGE(0);
  STAGE(1);
#pragma unroll
  for (int it = 0; it < NITER; ++it) {
    if (it + 2 < NITER) STAGE((it + 2) % 3);
    if (it < NITER - 2)
      asm volatile("s_waitcnt vmcnt(20)" ::: "memory");
    else if (it == NITER - 2)
      asm volatile("s_waitcnt vmcnt(10)" ::: "memory");
    else
      asm volatile("s_waitcnt vmcnt(0)" ::: "memory");
    __builtin_amdgcn_sched_barrier(0);
    __builtin_amdgcn_s_barrier();   // all waves' slab-it loads landed
    __builtin_amdgcn_sched_barrier(0);
    const char* cb = smem + (it % 3) * BUFSZ;
#pragma unroll
    for (int kk = 0; kk < 4; ++kk) {
      const int rowA = wm * 32 + (lane & 31);
      const int kc = kk * 2 + (lane >> 5);
      short8 af = *(const short8*)(cb +
          (((ks * 64 + rowA) * 8) + (kc ^ (rowA & 7))) * 16);
      const int nl = lane & 31;
      const int kcs2 = kc ^ (nl & 7);
      short8 bR = *(const short8*)(cb + 16384 +
          ((((0 * 2 + ks) * 32 + nl) * 8) + kcs2) * 16);
      short8 bZ = *(const short8*)(cb + 16384 +
          ((((1 * 2 + ks) * 32 + nl) * 8) + kcs2) * 16);
      short8 bN = *(const short8*)(cb + 16384 +
          ((((2 * 2 + ks) * 32 + nl) * 8) + kcs2) * 16);
      accR = __builtin_amdgcn_mfma_f32_32x32x16_bf16(af, bR, accR, 0, 0, 0);
      accZ = __builtin_amdgcn_mfma_f32_32x32x16_bf16(af, bZ, accZ, 0, 0, 0);
      accN = __builtin_amdgcn_mfma_f32_32x32x16_bf16(af, bN, accN, 0, 0, 0);
    }
    asm volatile("s_waitcnt lgkmcnt(0)" ::: "memory");
    __builtin_amdgcn_sched_barrier(0);
    __builtin_amdgcn_s_barrier();   // all waves done reading buf(it%3)
    __builtin_amdgcn_sched_barrier(0);
  }
#undef STAGE
  __syncthreads();

  // ---- cross-wave (K-split) reduction through LDS (aliases slab0) ----
  float* red = (float*)smem;
  if (ks == 1) {
#pragma unroll
    for (int j = 0; j < 16; ++j) {
      red[((wm * 3 + 0) * 16 + j) * 64 + lane] = accR[j];
      red[((wm * 3 + 1) * 16 + j) * 64 + lane] = accZ[j];
      red[((wm * 3 + 2) * 16 + j) * 64 + lane] = accN[j];
    }
  }
  __syncthreads();
  if (ks == 0) {
    const int nloc = lane & 31;
    const int n = nb * 32 + nloc;
    const float br = bias4[n], bz = bias4[1024 + n];
    const float bin = bias4[2048 + n], bhn = bias4[3072 + n];
#pragma unroll
    for (int j = 0; j < 16; ++j) {
      // C/D layout (32x32): col = lane&31, row = 4*(lane>>5)+(j&3)+8*(j>>2)
      int mloc = 4 * (lane >> 5) + (j & 3) + 8 * (j >> 2);
      int b = rowbase + wm * 32 + mloc;
      float r1 = red[((wm * 3 + 0) * 16 + j) * 64 + lane];
      float z1 = red[((wm * 3 + 1) * 16 + j) * 64 + lane];
      float n1 = red[((wm * 3 + 2) * 16 + j) * 64 + lane];
      float rt = accR[j] + r1 + br;
      float zt = accZ[j] + z1 + bz;
      float hn, npre;
      if (L0T) {
        int tok = (t == 0) ? 1 : inputs[b * S_ + (t - 1)];
        const float* tb = table + tok * 3072;
        const float* gpv = gprec + b * 3072;
        rt += tb[n] + gpv[n];
        zt += tb[1024 + n] + gpv[1024 + n];
        hn = accN[j] + n1 + bhn;        // both halves are whh
        npre = tb[2048 + n] + gpv[2048 + n];
      } else {
        hn = n1 + bhn;          // ks=1 half == whh part
        npre = accN[j] + bin;   // ks=0 half == wih part
      }
      float r = 1.f / (1.f + __expf(-rt));
      float z = 1.f / (1.f + __expf(-zt));
      float nn = npre + r * hn;
      float e2 = __expf(2.f * nn);
      float th = 1.f - 2.f / (e2 + 1.f);  // tanh, inf-safe
      unsigned hpb = (hreg[j >> 1] >> ((j & 1) * 16)) & 0xffffu;
      float hp = us2f((unsigned short)hpb);
      float hv = (1.f - z) * th + z * hp;
      unsigned short hb =
          __builtin_bit_cast(unsigned short, __float2bfloat16(hv));
      if (j & 1)
        hreg[j >> 1] = (hreg[j >> 1] & 0x0000ffffu) | ((unsigned)hb << 16);
      else
        hreg[j >> 1] = (hreg[j >> 1] & 0xffff0000u) | (unsigned)hb;
      // sc0 store: through L1 into the XCD-local L2 (coherent for same-XCD
      // readers after the xbar).
      asm volatile("global_store_short %0, %1, off sc0"
                   :: "v"(hout + b * H_ + n), "v"((unsigned)hb) : "memory");
    }
  }
}

// ---------------------------------------------------------------------------
// OUT tile: 2 batch rows per block (rows rowbase+2c, +1); h2 read sc0 from
// the XCD-local L2; logits stored NT. hs region at smem+24576 (above red).
// ---------------------------------------------------------------------------
__device__ __forceinline__ void out_tile(
    int rowbase, int c, const bf16* __restrict__ h2,
    const bf16* __restrict__ owTv, const float* __restrict__ logitde,
    float* __restrict__ out, int t, char* smem)
{
  float* hs = (float*)(smem + 24576);  // 2 rows x 1024 f32 = 8KB
  const int tid = threadIdx.x;
  const int b0 = rowbase + 2 * c;
  {
    const unsigned* pb = (const unsigned*)(h2 + b0 * H_) + tid;
    unsigned v0, v1, v2, v3;
    asm volatile(
        "global_load_dword %0, %4, off sc0\n\t"
        "global_load_dword %1, %4, off offset:1024 sc0\n\t"
        "global_load_dword %2, %4, off offset:2048 sc0\n\t"
        "global_load_dword %3, %4, off offset:3072 sc0\n\t"
        "s_waitcnt vmcnt(0)"
        : "=&v"(v0), "=&v"(v1), "=&v"(v2), "=&v"(v3)
        : "v"(pb)
        : "memory");
    hs[2 * tid] = us2f((unsigned short)(v0 & 0xffffu));
    hs[2 * tid + 1] = us2f((unsigned short)(v0 >> 16));
    hs[2 * (tid + 256)] = us2f((unsigned short)(v1 & 0xffffu));
    hs[2 * (tid + 256) + 1] = us2f((unsigned short)(v1 >> 16));
    hs[2 * (tid + 512)] = us2f((unsigned short)(v2 & 0xffffu));
    hs[2 * (tid + 512) + 1] = us2f((unsigned short)(v2 >> 16));
    hs[2 * (tid + 768)] = us2f((unsigned short)(v3 & 0xffffu));
    hs[2 * (tid + 768) + 1] = us2f((unsigned short)(v3 >> 16));
  }
  __syncthreads();
  const int v = tid & 127, r = tid >> 7;
  if (v < V_) {
    float acc = logitde[(b0 + r) * V_ + v];
    const ushort8* row = (const ushort8*)(owTv + v * H_);
    const float* h = hs + r * H_;
#pragma unroll 4
    for (int k8 = 0; k8 < H_ / 8; ++k8) {
      ushort8 wv = row[k8];
#pragma unroll
      for (int i = 0; i < 8; ++i) acc += h[k8 * 8 + i] * us2f(wv[i]);
    }
    __builtin_nontemporal_store(acc, &out[((b0 + r) * S_ + t) * V_ + v]);
  }
  __syncthreads();
}

// ---------------------------------------------------------------------------
// Persistent scan kernel: entire 200-step decode; only XCD-local barriers.
//   X_t: L1(t) + OUT(t-1);  Y_t: L2(t) + L0(t+1).
// ---------------------------------------------------------------------------
__global__ __launch_bounds__(256, 1) void scan_kernel(
    const int* __restrict__ inputs,
    const bf16* __restrict__ Wp0, const bf16* __restrict__ Wp1,
    const bf16* __restrict__ Wp2, const float* __restrict__ bias4all,
    const float* __restrict__ table, const float* __restrict__ gprec0,
    const bf16* __restrict__ owTv, const float* __restrict__ logitde,
    bf16* __restrict__ hbuf, float* __restrict__ out,
    unsigned* __restrict__ flags)
{
  __shared__ char smem[3 * BUFSZ];
  __shared__ int s_g, s_c;
  const int tid = threadIdx.x;
  const int lane = tid & 63;
  const int w = tid >> 6;
  const int wm = w & 1, ks = w >> 1;

  // ---- self-assign XCD group g and slot c (no blockIdx->XCD assumption) ----
  if (tid == 0) {
    unsigned x;
    asm volatile("s_getreg_b32 %0, hwreg(HW_REG_XCC_ID)" : "=s"(x));
    x &= 7u;
    s_g = (int)x;
    s_c = (int)(atomicAdd(flags + 512 + x, 1u) & 31u);
  }
  __syncthreads();
  const int g = s_g, c = s_c;
  const int rowbase = g * 64;  // this XCD's 64 batch rows
  const int nb = c;            // this block's 32-column slice
  unsigned gen = 0;
  bool dead = false;

#define HBD(par, l) (hbuf + ((par) * 3 + (l)) * (B_ * H_))
  // ---- register-resident hprev init (all layers start at hinit) ----
  unsigned h0r[8], h1r[8], h2r[8];
  if (ks == 0) {
#pragma unroll
    for (int jj = 0; jj < 8; ++jj) {
      int mloc = 4 * (lane >> 5) + ((2 * jj) & 3) + 8 * (jj >> 1);
      int b = rowbase + wm * 32 + mloc;
      int n = nb * 32 + (lane & 31);
      unsigned lo = *(const unsigned short*)(HBD(0, 0) + b * H_ + n);
      unsigned hi = *(const unsigned short*)(HBD(0, 0) + (b + 1) * H_ + n);
      h0r[jj] = lo | (hi << 16);
      h1r[jj] = h0r[jj];
      h2r[jj] = h0r[jj];
    }
  }

  // Prologue: L0 step 0 (h_l(-1) lives in parity-0 buffers).
  gates_tile<1024, true>(rowbase, nb, HBD(0, 0), HBD(0, 0), Wp0, bias4all,
                         table, gprec0, inputs, 0, HBD(1, 0), h0r, smem);
  xbar(flags, g, c, ++gen, dead);

  for (int t = 0; t < S_; ++t) {
    const int pp = t & 1, pc = 1 - pp;  // h_l(t) lives in parity pc
    // X: L1(t) [A = h0(t) | h1(t-1)] + OUT(t-1)
    gates_tile<2048, false>(rowbase, nb, HBD(pc, 0), HBD(pp, 1), Wp1,
                            bias4all + 4096, nullptr, nullptr, nullptr, t,
                            HBD(pc, 1), h1r, smem);
    if (t > 0)
      out_tile(rowbase, c, HBD(pp, 2), owTv, logitde, out, t - 1, smem);
    xbar(flags, g, c, ++gen, dead);
    // Y: L2(t) [A = h1(t) | h2(t-1)] + L0(t+1) [A = h0(t)]
    gates_tile<2048, false>(rowbase, nb, HBD(pc, 1), HBD(pp, 2), Wp2,
                            bias4all + 8192, nullptr, nullptr, nullptr, t,
                            HBD(pc, 2), h2r, smem);
    if (t + 1 < S_)
      gates_tile<1024, true>(rowbase, nb, HBD(pc, 0), HBD(pc, 0), Wp0,
                             bias4all, table, gprec0, inputs, t + 1,
                             HBD(pp, 0), h0r, smem);
    xbar(flags, g, c, ++gen, dead);
  }
  // Epilogue: OUT(199); h2(199) parity = (199+1)&1 = 0.
  out_tile(rowbase, c, HBD(0, 2), owTv, logitde, out, S_ - 1, smem);
#undef HBD
}

// ---------------------------------------------------------------------------
// fp32 precompute GEMM: C[m][n] = sum_k A[m*lda+k]*W[n*ldw+woff+k] + bias[n]
// ---------------------------------------------------------------------------
__global__ __launch_bounds__(256) void pgemm(
    const float* __restrict__ A, int lda, const float* __restrict__ W, int ldw,
    int woff, const float* __restrict__ bias, float* __restrict__ C,
    int M, int N, int K)
{
  __shared__ float As[64][33];
  __shared__ float Ws[64][33];
  const int tid = threadIdx.x;
  const int tx = tid & 15, ty = tid >> 4;
  const int mb = blockIdx.x * 64, nb = blockIdx.y * 64;
  float acc[4][4];
#pragma unroll
  for (int i = 0; i < 4; ++i)
#pragma unroll
    for (int j = 0; j < 4; ++j) acc[i][j] = 0.f;

  for (int k0 = 0; k0 < K; k0 += 32) {
#pragma unroll
    for (int s = 0; s < 8; ++s) {
      int idx = s * 256 + tid;
      int r = idx >> 5, cc = idx & 31;
      int m = mb + r;
      As[r][cc] = (m < M) ? A[m * lda + k0 + cc] : 0.f;
      int n = nb + r;
      Ws[r][cc] = (n < N) ? W[n * ldw + woff + k0 + cc] : 0.f;
    }
    __syncthreads();
#pragma unroll 8
    for (int kk = 0; kk < 32; ++kk) {
      float a[4], ww[4];
#pragma unroll
      for (int i = 0; i < 4; ++i) a[i] = As[ty * 4 + i][kk];
#pragma unroll
      for (int j = 0; j < 4; ++j) ww[j] = Ws[tx * 4 + j][kk];
#pragma unroll
      for (int i = 0; i < 4; ++i)
#pragma unroll
        for (int j = 0; j < 4; ++j) acc[i][j] += a[i] * ww[j];
    }
    __syncthreads();
  }
#pragma unroll
  for (int i = 0; i < 4; ++i) {
    int m = mb + ty * 4 + i;
    if (m >= M) continue;
#pragma unroll
    for (int j = 0; j < 4; ++j) {
      int n = nb + tx * 4 + j;
      if (n < N) C[m * N + n] = acc[i][j] + (bias ? bias[n] : 0.f);
    }
  }
}

// --------------------------- small pack kernels ----------------------------
__global__ void k_de(const float* __restrict__ z, const float* __restrict__ c,
                     float* __restrict__ de) {
  int i = blockIdx.x * 256 + threadIdx.x;  // 512*1024
  int b = i >> 10, q = i & 1023;
  de[i] = (q < 512) ? z[b * 512 + q] : c[b * 512 + (q - 512)];
}

__global__ void k_wpack(const float* __restrict__ wih,
                        const float* __restrict__ whh, bf16* __restrict__ Wp,
                        int ktshift) {
  int KT = 1 << ktshift;
  int i = blockIdx.x * 256 + threadIdx.x;
  if (i >= 3072 * KT) return;
  int k = i & (KT - 1);
  int row = i >> ktshift;  // g*1024 + n
  float v = (k < 1024) ? wih[row * 1024 + k] : whh[row * 1024 + (k - 1024)];
  Wp[i] = __float2bfloat16(v);
}

__global__ void k_bias4(const float* __restrict__ bih,
                        const float* __restrict__ bhh, float* __restrict__ dst,
                        int l0) {
  int n = blockIdx.x * 256 + threadIdx.x;
  if (n >= 1024) return;
  dst[n] = l0 ? bhh[n] : bih[n] + bhh[n];
  dst[1024 + n] = l0 ? bhh[1024 + n] : bih[1024 + n] + bhh[1024 + n];
  dst[2048 + n] = l0 ? 0.f : bih[2048 + n];
  dst[3072 + n] = bhh[2048 + n];
}

__global__ void k_owt(const float* __restrict__ out_w, bf16* __restrict__ owTv) {
  int i = blockIdx.x * 256 + threadIdx.x;  // 100*1024
  if (i >= V_ * H_) return;
  int v = i >> 10, k = i & 1023;
  owTv[i] = __float2bfloat16(out_w[v * 2048 + k]);
}

__global__ void k_hinit(const float* __restrict__ hinit, bf16* __restrict__ h0,
                        bf16* __restrict__ h1, bf16* __restrict__ h2) {
  int i = blockIdx.x * 256 + threadIdx.x;  // 512*1024
  bf16 v = __float2bfloat16(hinit[i]);
  h0[i] = v; h1[i] = v; h2[i] = v;
}

__global__ void k_zero(unsigned* __restrict__ p) {
  int i = threadIdx.x;
#pragma unroll
  for (int j = 0; j < 4; ++j) p[j * 256 + i] = 0u;  // flags 512 + counters 8
}

// ---------------------------------------------------------------------------
extern "C" void kernel_launch(void* const* d_in, const int* in_sizes, int n_in,
                              void* d_out, int out_size, void* d_ws,
                              size_t ws_size, hipStream_t stream) {
  const int* inputs = (const int*)d_in[0];
  const float* z = (const float*)d_in[1];
  const float* cond = (const float*)d_in[2];
  // d_in[3] = temperature (ignored: >=1 -> always teacher-forced)
  const float* emb = (const float*)d_in[4];
  const float* i2h_w = (const float*)d_in[5];
  const float* i2h_b = (const float*)d_in[6];
  const float* out_w = (const float*)d_in[7];
  const float* out_b = (const float*)d_in[8];
  const float* wih0 = (const float*)d_in[9];
  const float* whh0 = (const float*)d_in[10];
  const float* bih0 = (const float*)d_in[11];
  const float* bhh0 = (const float*)d_in[12];
  const float* wih1 = (const float*)d_in[13];
  const float* whh1 = (const float*)d_in[14];
  const float* bih1 = (const float*)d_in[15];
  const float* bhh1 = (const float*)d_in[16];
  const float* wih2 = (const float*)d_in[17];
  const float* whh2 = (const float*)d_in[18];
  const float* bih2 = (const float*)d_in[19];
  const float* bhh2 = (const float*)d_in[20];
  float* out = (float*)d_out;

  char* p = (char*)d_ws;
  float* de = (float*)(p + 0);                 //  2 MB
  float* gprec0 = (float*)(p + 2097152);       //  6.29 MB
  float* table = (float*)(p + 8388608);        //  1.23 MB
  float* hinit = (float*)(p + 9617408);        //  2 MB (dead after k_hinit)
  float* logitde = (float*)(p + 11714560);     //  0.2 MB
  float* bias4 = (float*)(p + 11919360);       //  48 KB [3][4][1024]
  bf16* Wp0 = (bf16*)(p + 11968512);           //  6.29 MB
  bf16* Wp1 = (bf16*)(p + 18259968);           // 12.58 MB
  bf16* Wp2 = (bf16*)(p + 30842880);           // 12.58 MB
  bf16* owTv = (bf16*)(p + 43425792);          //  0.2 MB
  bf16* hbuf = (bf16*)(p + 43630592);          //  6.29 MB [2][3][512][1024]
  unsigned* flags = (unsigned*)(p + 9617408);  // 4 KB, reuses dead hinit space

  // ---- one-time precompute (per call; weights re-restored each call) ----
  k_de<<<2048, 256, 0, stream>>>(z, cond, de);
  pgemm<<<dim3(8, 48), 256, 0, stream>>>(de, 1024, wih0, 1536, 512, bih0,
                                         gprec0, 512, 3072, 1024);
  pgemm<<<dim3(2, 48), 256, 0, stream>>>(emb, 512, wih0, 1536, 0, nullptr,
                                         table, 100, 3072, 512);
  pgemm<<<dim3(8, 16), 256, 0, stream>>>(de, 1024, i2h_w, 1024, 0, i2h_b,
                                         hinit, 512, 1024, 1024);
  pgemm<<<dim3(8, 2), 256, 0, stream>>>(de, 1024, out_w, 2048, 1024, out_b,
                                        logitde, 512, 100, 1024);
  k_bias4<<<4, 256, 0, stream>>>(bhh0, bhh0, bias4, 1);
  k_bias4<<<4, 256, 0, stream>>>(bih1, bhh1, bias4 + 4096, 0);
  k_bias4<<<4, 256, 0, stream>>>(bih2, bhh2, bias4 + 8192, 0);
  k_wpack<<<(3072 * 1024 + 255) / 256, 256, 0, stream>>>(whh0, whh0, Wp0, 10);
  k_wpack<<<(3072 * 2048 + 255) / 256, 256, 0, stream>>>(wih1, whh1, Wp1, 11);
  k_wpack<<<(3072 * 2048 + 255) / 256, 256, 0, stream>>>(wih2, whh2, Wp2, 11);
  k_owt<<<400, 256, 0, stream>>>(out_w, owTv);
#define HB(par, l) (hbuf + ((par) * 3 + (l)) * (B_ * H_))
  k_hinit<<<2048, 256, 0, stream>>>(hinit, HB(0, 0), HB(0, 1), HB(0, 2));
#undef HB
  k_zero<<<1, 256, 0, stream>>>(flags);  // after k_hinit (flags alias hinit)

  // ---- entire 200-step scan: one persistent kernel, XCD-local sync only ----
  scan_kernel<<<NBLK, 256, 0, stream>>>(inputs, Wp0, Wp1, Wp2, bias4, table,
                                        gprec0, owTv, logitde, hbuf, out,
                                        flags);
}

// Round 7
// 10468.553 us; speedup vs baseline: 4.7738x; 4.7738x over previous
//
#include <hip/hip_runtime.h>
#include <hip/hip_bf16.h>

// DecoderRNN: 3-layer GRU, B=512, S=200, H=1024, V=100, teacher-forced scan.
// v7: launch-based again (free bulk coherence), but PIPELINE-SKEWED:
//   one launch tt computes { L0(tt), L1(tt-1), L2(tt-2), OUT(tt-3) } -- all
//   mutually independent under teacher forcing; each depends only on launch
//   tt-1. 203 launches of ONE 1024-block kernel replace 800 launches of 4
//   kernels: 4x fewer launch boundaries, and the four phases' memory stalls
//   overlap (4 blocks/CU of heterogeneous work).
// Math is bit-identical to the 20.2ms r0 baseline (plain cached loads/stores,
// no sc bits, no device-scope flags). h buffers are 2-deep by launch parity:
//   L0(tt)  : hprev h0[(tt-1)&1] -> writes h0[tt&1]
//   L1(tt-1): A=[h0[(tt-1)&1] | h1[tt&1]]       -> writes h1[(tt-1)&1]
//   L2(tt-2): A=[h1[tt&1]     | h2[(tt-1)&1]]   -> writes h2[tt&1]
//   OUT(tt-3): reads h2[(tt-1)&1]
// (all read/write pairs land in opposite parities; verified per role.)

typedef __hip_bfloat16 bf16;
typedef __attribute__((ext_vector_type(8))) short short8;
typedef __attribute__((ext_vector_type(8))) unsigned short ushort8;
typedef __attribute__((ext_vector_type(16))) float f32x16;

#define B_ 512
#define S_ 200
#define H_ 1024
#define V_ 100

__device__ __forceinline__ float bf2f(bf16 x) { return __bfloat162float(x); }
__device__ __forceinline__ float us2f(unsigned short u) {
  return __uint_as_float(((unsigned)u) << 16);
}

// ---------------------------------------------------------------------------
// Gates tile: 64M x 32N x 3 gates of h_l(t). 4 waves: wm = w&1 (M-half),
// ks = w>>1 (K-half). Single 40KB LDS slab, __syncthreads-staged (r0's proven
// flow), hoisted +128B/slab staging pointers. GRU epilogue on ks==0 waves,
// hprev read from global (plain cached), plain h stores.
// ---------------------------------------------------------------------------
template <int KTOT, bool L0T>
__device__ __forceinline__ void gates_tile(
    int mb, int nb,
    const bf16* __restrict__ A0,      // k in [0,1024)
    const bf16* __restrict__ A1,      // k in [1024,2048) (unused if KTOT=1024)
    const bf16* __restrict__ Wp,      // [3][1024][KTOT]
    const float* __restrict__ bias4,  // [4][1024]
    const float* __restrict__ table,  // [100][3072] (L0 only)
    const float* __restrict__ gprec,  // [512][3072] (L0 only)
    const int* __restrict__ inputs,   // [512][200]  (L0 only)
    int t,
    const bf16* __restrict__ hprev,   // h_l(t-1) [512][1024]
    bf16* __restrict__ hout,          // h_l(t)   [512][1024]
    char* smem)
{
  constexpr int KH = KTOT / 2;
  constexpr int NITER = KH / 64;
  const int tid = threadIdx.x;
  const int lane = tid & 63;
  const int w = tid >> 6;
  const int wm = w & 1, ks = w >> 1;

  // ---- staging source pointers; +128B per k-slab ----
  // c<4: A granule [ksA][row 0..63][kcs 0..7], kc = kcs ^ (row&7).
  // c>=4: W granule [g][ksB][nl 0..31][kcs 0..7].
  const char* gp[10];
#pragma unroll
  for (int c = 0; c < 10; ++c) {
    const int G = c * 256 + tid;
    if (c < 4) {
      int ksA = G >> 9, row = (G >> 3) & 63, kcs = G & 7;
      int kc = kcs ^ (row & 7);
      int k = ksA * KH + kc * 8;
      const bf16* src = (KTOT == 2048 && k >= 1024) ? A1 : A0;
      gp[c] = (const char*)(src + ((mb * 64 + row) * H_ + (k & 1023)));
    } else {
      int Gb = G - 1024;
      int g = Gb >> 9, ksB = (Gb >> 8) & 1, nl = (Gb >> 3) & 31, kcs = Gb & 7;
      int kc = kcs ^ (nl & 7);
      int k0 = ksB * KH + kc * 8;
      gp[c] = (const char*)(Wp + ((g * 1024 + nb * 32 + nl) * KTOT + k0));
    }
  }

  f32x16 accR, accZ, accN;
#pragma unroll
  for (int j = 0; j < 16; ++j) { accR[j] = 0.f; accZ[j] = 0.f; accN[j] = 0.f; }

  for (int it = 0; it < NITER; ++it) {
    // ---- stage this slab (all plain cached; launch gives coherence) ----
#pragma unroll
    for (int c = 0; c < 10; ++c) {
      char* lp = smem + (c * 256 + w * 64) * 16;  // wave-uniform base
      __builtin_amdgcn_global_load_lds(
          (const __attribute__((address_space(1))) void*)gp[c],
          (__attribute__((address_space(3))) void*)lp, 16, 0, 0);
      gp[c] += 128;
    }
    __syncthreads();
    // ---- compute: 4 ksteps of 16 over this 64-k slab of my K-half ----
#pragma unroll
    for (int kk = 0; kk < 4; ++kk) {
      const int rowA = wm * 32 + (lane & 31);
      const int kc = kk * 2 + (lane >> 5);
      short8 af = *(const short8*)(smem +
          (((ks * 64 + rowA) * 8) + (kc ^ (rowA & 7))) * 16);
      const int nl = lane & 31;
      const int kcs2 = kc ^ (nl & 7);
      short8 bR = *(const short8*)(smem + 16384 +
          ((((0 * 2 + ks) * 32 + nl) * 8) + kcs2) * 16);
      short8 bZ = *(const short8*)(smem + 16384 +
          ((((1 * 2 + ks) * 32 + nl) * 8) + kcs2) * 16);
      short8 bN = *(const short8*)(smem + 16384 +
          ((((2 * 2 + ks) * 32 + nl) * 8) + kcs2) * 16);
      accR = __builtin_amdgcn_mfma_f32_32x32x16_bf16(af, bR, accR, 0, 0, 0);
      accZ = __builtin_amdgcn_mfma_f32_32x32x16_bf16(af, bZ, accZ, 0, 0, 0);
      accN = __builtin_amdgcn_mfma_f32_32x32x16_bf16(af, bN, accN, 0, 0, 0);
    }
    __syncthreads();
  }

  // ---- cross-wave (K-split) reduction through LDS ----
  float* red = (float*)smem;
  if (ks == 1) {
#pragma unroll
    for (int j = 0; j < 16; ++j) {
      red[((wm * 3 + 0) * 16 + j) * 64 + lane] = accR[j];
      red[((wm * 3 + 1) * 16 + j) * 64 + lane] = accZ[j];
      red[((wm * 3 + 2) * 16 + j) * 64 + lane] = accN[j];
    }
  }
  __syncthreads();
  if (ks == 0) {
    const int nloc = lane & 31;
    const int n = nb * 32 + nloc;
    const float br = bias4[n], bz = bias4[1024 + n];
    const float bin = bias4[2048 + n], bhn = bias4[3072 + n];
#pragma unroll
    for (int j = 0; j < 16; ++j) {
      // C/D layout (32x32): col = lane&31, row = 4*(lane>>5)+(j&3)+8*(j>>2)
      int mloc = 4 * (lane >> 5) + (j & 3) + 8 * (j >> 2);
      int b = mb * 64 + wm * 32 + mloc;
      float r1 = red[((wm * 3 + 0) * 16 + j) * 64 + lane];
      float z1 = red[((wm * 3 + 1) * 16 + j) * 64 + lane];
      float n1 = red[((wm * 3 + 2) * 16 + j) * 64 + lane];
      float rt = accR[j] + r1 + br;
      float zt = accZ[j] + z1 + bz;
      float hn, npre;
      if (L0T) {
        int tok = (t == 0) ? 1 : inputs[b * S_ + (t - 1)];
        const float* tb = table + tok * 3072;
        const float* gpv = gprec + b * 3072;
        rt += tb[n] + gpv[n];
        zt += tb[1024 + n] + gpv[1024 + n];
        hn = accN[j] + n1 + bhn;            // both halves are whh
        npre = tb[2048 + n] + gpv[2048 + n];  // i_n from table (incl bih0)
      } else {
        hn = n1 + bhn;          // ks=1 half == whh part
        npre = accN[j] + bin;   // ks=0 half == wih part
      }
      float r = 1.f / (1.f + __expf(-rt));
      float z = 1.f / (1.f + __expf(-zt));
      float nn = npre + r * hn;
      float e2 = __expf(2.f * nn);
      float th = 1.f - 2.f / (e2 + 1.f);  // tanh, inf-safe
      float hp = bf2f(hprev[b * H_ + n]);
      float hv = (1.f - z) * th + z * hp;
      hout[b * H_ + n] = __float2bfloat16(hv);
    }
  }
}

// ---------------------------------------------------------------------------
// OUT tile: 2 batch rows per role-block (256 blocks cover 512 rows).
// ---------------------------------------------------------------------------
__device__ __forceinline__ void out_tile(
    int i, const bf16* __restrict__ h2, const bf16* __restrict__ owTv,
    const float* __restrict__ logitde, float* __restrict__ out, int t,
    char* smem)
{
  float* hs = (float*)smem;  // 2 rows x 1024 f32 = 8KB
  const int tid = threadIdx.x;
  const int b0 = i * 2;
  const unsigned short* h2u = (const unsigned short*)(h2 + b0 * H_);
  for (int k = tid; k < 2 * H_; k += 256) hs[k] = us2f(h2u[k]);
  __syncthreads();
  const int v = tid & 127, r = tid >> 7;
  if (v < V_) {
    float acc = logitde[(b0 + r) * V_ + v];
    const ushort8* row = (const ushort8*)(owTv + v * H_);
    const float* h = hs + r * H_;
#pragma unroll 4
    for (int k8 = 0; k8 < H_ / 8; ++k8) {
      ushort8 wv = row[k8];
#pragma unroll
      for (int q = 0; q < 8; ++q) acc += h[k8 * 8 + q] * us2f(wv[q]);
    }
    out[((b0 + r) * S_ + t) * V_ + v] = acc;
  }
}

// ---------------------------------------------------------------------------
// One pipeline-skewed step: 1024 blocks, role = bid>>8.
//   role 0: L0(tt)   role 1: L1(tt-1)   role 2: L2(tt-2)   role 3: OUT(tt-3)
// ---------------------------------------------------------------------------
__global__ __launch_bounds__(256) void step_kernel(
    int tt, const int* __restrict__ inputs,
    const bf16* __restrict__ Wp0, const bf16* __restrict__ Wp1,
    const bf16* __restrict__ Wp2, const float* __restrict__ bias4all,
    const float* __restrict__ table, const float* __restrict__ gprec0,
    const bf16* __restrict__ owTv, const float* __restrict__ logitde,
    bf16* __restrict__ hbuf, float* __restrict__ out)
{
  __shared__ char smem[40960];
  const int bid = blockIdx.x;
  const int role = bid >> 8;
  const int i = bid & 255;
  // Within each role, XCD = (role*256+i)%8 = i%8 owns nb in {4k..4k+3}
  // every launch -> within-launch weight-slice L2 reuse (8 mb share it).
  const int mb = i >> 5;
  const int nb = (i & 7) * 4 + ((i >> 3) & 3);
  const int pA = (tt - 1) & 1, pB = tt & 1;
#define HB(par, l) (hbuf + ((par) * 3 + (l)) * (B_ * H_))
  if (role == 0) {
    const int t = tt;
    if (t < S_) {
      const bf16* hp = HB(pA, 0);
      gates_tile<1024, true>(mb, nb, hp, hp, Wp0, bias4all, table, gprec0,
                             inputs, t, hp, HB(pB, 0), smem);
    }
  } else if (role == 1) {
    const int t = tt - 1;
    if (t >= 0 && t < S_)
      gates_tile<2048, false>(mb, nb, HB(pA, 0), HB(pB, 1), Wp1,
                              bias4all + 4096, nullptr, nullptr, nullptr, t,
                              HB(pB, 1), HB(pA, 1), smem);
  } else if (role == 2) {
    const int t = tt - 2;
    if (t >= 0 && t < S_)
      gates_tile<2048, false>(mb, nb, HB(pB, 1), HB(pA, 2), Wp2,
                              bias4all + 8192, nullptr, nullptr, nullptr, t,
                              HB(pA, 2), HB(pB, 2), smem);
  } else {
    const int t = tt - 3;
    if (t >= 0 && t < S_)
      out_tile(i, HB(pA, 2), owTv, logitde, out, t, smem);
  }
#undef HB
}

// ---------------------------------------------------------------------------
// fp32 precompute GEMM: C[m][n] = sum_k A[m*lda+k]*W[n*ldw+woff+k] + bias[n]
// ---------------------------------------------------------------------------
__global__ __launch_bounds__(256) void pgemm(
    const float* __restrict__ A, int lda, const float* __restrict__ W, int ldw,
    int woff, const float* __restrict__ bias, float* __restrict__ C,
    int M, int N, int K)
{
  __shared__ float As[64][33];
  __shared__ float Ws[64][33];
  const int tid = threadIdx.x;
  const int tx = tid & 15, ty = tid >> 4;
  const int mb = blockIdx.x * 64, nb = blockIdx.y * 64;
  float acc[4][4];
#pragma unroll
  for (int ii = 0; ii < 4; ++ii)
#pragma unroll
    for (int j = 0; j < 4; ++j) acc[ii][j] = 0.f;

  for (int k0 = 0; k0 < K; k0 += 32) {
#pragma unroll
    for (int s = 0; s < 8; ++s) {
      int idx = s * 256 + tid;
      int r = idx >> 5, c = idx & 31;
      int m = mb + r;
      As[r][c] = (m < M) ? A[m * lda + k0 + c] : 0.f;
      int n = nb + r;
      Ws[r][c] = (n < N) ? W[n * ldw + woff + k0 + c] : 0.f;
    }
    __syncthreads();
#pragma unroll 8
    for (int kk = 0; kk < 32; ++kk) {
      float a[4], ww[4];
#pragma unroll
      for (int ii = 0; ii < 4; ++ii) a[ii] = As[ty * 4 + ii][kk];
#pragma unroll
      for (int j = 0; j < 4; ++j) ww[j] = Ws[tx * 4 + j][kk];
#pragma unroll
      for (int ii = 0; ii < 4; ++ii)
#pragma unroll
        for (int j = 0; j < 4; ++j) acc[ii][j] += a[ii] * ww[j];
    }
    __syncthreads();
  }
#pragma unroll
  for (int ii = 0; ii < 4; ++ii) {
    int m = mb + ty * 4 + ii;
    if (m >= M) continue;
#pragma unroll
    for (int j = 0; j < 4; ++j) {
      int n = nb + tx * 4 + j;
      if (n < N) C[m * N + n] = acc[ii][j] + (bias ? bias[n] : 0.f);
    }
  }
}

// --------------------------- small pack kernels ----------------------------
__global__ void k_de(const float* __restrict__ z, const float* __restrict__ c,
                     float* __restrict__ de) {
  int i = blockIdx.x * 256 + threadIdx.x;  // 512*1024
  int b = i >> 10, q = i & 1023;
  de[i] = (q < 512) ? z[b * 512 + q] : c[b * 512 + (q - 512)];
}

__global__ void k_wpack(const float* __restrict__ wih,
                        const float* __restrict__ whh, bf16* __restrict__ Wp,
                        int ktshift) {
  int KT = 1 << ktshift;
  int i = blockIdx.x * 256 + threadIdx.x;
  if (i >= 3072 * KT) return;
  int k = i & (KT - 1);
  int row = i >> ktshift;  // g*1024 + n
  float v = (k < 1024) ? wih[row * 1024 + k] : whh[row * 1024 + (k - 1024)];
  Wp[i] = __float2bfloat16(v);
}

__global__ void k_bias4(const float* __restrict__ bih,
                        const float* __restrict__ bhh, float* __restrict__ dst,
                        int l0) {
  int n = blockIdx.x * 256 + threadIdx.x;
  if (n >= 1024) return;
  dst[n] = l0 ? bhh[n] : bih[n] + bhh[n];
  dst[1024 + n] = l0 ? bhh[1024 + n] : bih[1024 + n] + bhh[1024 + n];
  dst[2048 + n] = l0 ? 0.f : bih[2048 + n];
  dst[3072 + n] = bhh[2048 + n];
}

__global__ void k_owt(const float* __restrict__ out_w, bf16* __restrict__ owTv) {
  int i = blockIdx.x * 256 + threadIdx.x;  // 100*1024
  if (i >= V_ * H_) return;
  int v = i >> 10, k = i & 1023;
  owTv[i] = __float2bfloat16(out_w[v * 2048 + k]);
}

__global__ void k_hinit(const float* __restrict__ hinit, bf16* __restrict__ h0,
                        bf16* __restrict__ h1, bf16* __restrict__ h2) {
  int i = blockIdx.x * 256 + threadIdx.x;  // 512*1024
  bf16 v = __float2bfloat16(hinit[i]);
  h0[i] = v; h1[i] = v; h2[i] = v;
}

// ---------------------------------------------------------------------------
extern "C" void kernel_launch(void* const* d_in, const int* in_sizes, int n_in,
                              void* d_out, int out_size, void* d_ws,
                              size_t ws_size, hipStream_t stream) {
  const int* inputs = (const int*)d_in[0];
  const float* z = (const float*)d_in[1];
  const float* cond = (const float*)d_in[2];
  // d_in[3] = temperature (ignored: >=1 -> always teacher-forced)
  const float* emb = (const float*)d_in[4];
  const float* i2h_w = (const float*)d_in[5];
  const float* i2h_b = (const float*)d_in[6];
  const float* out_w = (const float*)d_in[7];
  const float* out_b = (const float*)d_in[8];
  const float* wih0 = (const float*)d_in[9];
  const float* whh0 = (const float*)d_in[10];
  const float* bih0 = (const float*)d_in[11];
  const float* bhh0 = (const float*)d_in[12];
  const float* wih1 = (const float*)d_in[13];
  const float* whh1 = (const float*)d_in[14];
  const float* bih1 = (const float*)d_in[15];
  const float* bhh1 = (const float*)d_in[16];
  const float* wih2 = (const float*)d_in[17];
  const float* whh2 = (const float*)d_in[18];
  const float* bih2 = (const float*)d_in[19];
  const float* bhh2 = (const float*)d_in[20];
  float* out = (float*)d_out;

  char* p = (char*)d_ws;
  float* de = (float*)(p + 0);                 //  2 MB
  float* gprec0 = (float*)(p + 2097152);       //  6.29 MB
  float* table = (float*)(p + 8388608);        //  1.23 MB
  float* hinit = (float*)(p + 9617408);        //  2 MB (dead after k_hinit)
  float* logitde = (float*)(p + 11714560);     //  0.2 MB
  float* bias4 = (float*)(p + 11919360);       //  48 KB [3][4][1024]
  bf16* Wp0 = (bf16*)(p + 11968512);           //  6.29 MB
  bf16* Wp1 = (bf16*)(p + 18259968);           // 12.58 MB
  bf16* Wp2 = (bf16*)(p + 30842880);           // 12.58 MB
  bf16* owTv = (bf16*)(p + 43425792);          //  0.2 MB
  bf16* hbuf = (bf16*)(p + 43630592);          //  6.29 MB [2][3][512][1024]

  // ---- one-time precompute (per call; weights are re-restored each call) ----
  k_de<<<2048, 256, 0, stream>>>(z, cond, de);
  pgemm<<<dim3(8, 48), 256, 0, stream>>>(de, 1024, wih0, 1536, 512, bih0,
                                         gprec0, 512, 3072, 1024);
  pgemm<<<dim3(2, 48), 256, 0, stream>>>(emb, 512, wih0, 1536, 0, nullptr,
                                         table, 100, 3072, 512);
  pgemm<<<dim3(8, 16), 256, 0, stream>>>(de, 1024, i2h_w, 1024, 0, i2h_b,
                                         hinit, 512, 1024, 1024);
  pgemm<<<dim3(8, 2), 256, 0, stream>>>(de, 1024, out_w, 2048, 1024, out_b,
                                        logitde, 512, 100, 1024);
  k_bias4<<<4, 256, 0, stream>>>(bhh0, bhh0, bias4, 1);
  k_bias4<<<4, 256, 0, stream>>>(bih1, bhh1, bias4 + 4096, 0);
  k_bias4<<<4, 256, 0, stream>>>(bih2, bhh2, bias4 + 8192, 0);
  k_wpack<<<(3072 * 1024 + 255) / 256, 256, 0, stream>>>(whh0, whh0, Wp0, 10);
  k_wpack<<<(3072 * 2048 + 255) / 256, 256, 0, stream>>>(wih1, whh1, Wp1, 11);
  k_wpack<<<(3072 * 2048 + 255) / 256, 256, 0, stream>>>(wih2, whh2, Wp2, 11);
  k_owt<<<400, 256, 0, stream>>>(out_w, owTv);
#define HB(par, l) (hbuf + ((par) * 3 + (l)) * (B_ * H_))
  // h_l(-1) is read from parity-1 buffers at the first active launch of
  // each role (tt=0: h0[1]; tt=1: h1[1]; tt=2: h2[1]).
  k_hinit<<<2048, 256, 0, stream>>>(hinit, HB(1, 0), HB(1, 1), HB(1, 2));
#undef HB

  // ---- pipeline-skewed scan: 203 launches, one fused step each ----
  for (int tt = 0; tt < S_ + 3; ++tt)
    step_kernel<<<1024, 256, 0, stream>>>(tt, inputs, Wp0, Wp1, Wp2, bias4,
                                          table, gprec0, owTv, logitde, hbuf,
                                          out);
}